// Round 7
// baseline (153.090 us; speedup 1.0000x reference)
//
#include <hip/hip_runtime.h>

#define B_ 32
#define T_ 2048
#define H_ 256
#define L_ 2049   // T_ + 1

// ---------------- helpers ----------------
__device__ inline double waveReduceD(double v) {
#pragma unroll
  for (int off = 32; off > 0; off >>= 1) v += __shfl_xor(v, off, 64);
  return v;
}

typedef float vfloat4 __attribute__((ext_vector_type(4)));
__device__ inline void nt_store4(float4 v, float* p) {
  vfloat4 t;
  t.x = v.x; t.y = v.y; t.z = v.z; t.w = v.w;
  __builtin_nontemporal_store(t, (vfloat4*)p);
}

// ---------------- K0: fold the two linear layers ----------------
// v[c] = sum_o W2[o] * W1[o,c]  (c in [0,512)),  c0 = W2.b1 + b2
__global__ void __launch_bounds__(256) k0_fold(
    const float* __restrict__ W1, const float* __restrict__ b1,
    const float* __restrict__ W2, const float* __restrict__ b2,
    double* __restrict__ vd, double* __restrict__ c0) {
  __shared__ double s_p[8][32];
  int tid = threadIdx.x;
  int cl = tid & 31, sl = tid >> 5;
  int c = blockIdx.x * 32 + cl;
  double acc0 = 0.0, acc1 = 0.0;   // dual acc: half the serial fp64 chain
#pragma unroll 4
  for (int o = sl * 64; o < sl * 64 + 64; o += 2) {
    acc0 += (double)W2[o] * (double)W1[o * 512 + c];
    acc1 += (double)W2[o + 1] * (double)W1[(o + 1) * 512 + c];
  }
  s_p[sl][cl] = acc0 + acc1;
  __syncthreads();
  if (sl == 0) {
    double v = 0.0;
#pragma unroll
    for (int i = 0; i < 8; ++i) v += s_p[i][cl];
    vd[c] = v;
  }
  if (blockIdx.x == 0) {
    __shared__ double red[256];
    double p = (double)W2[tid] * (double)b1[tid] +
               (double)W2[tid + 256] * (double)b1[tid + 256];
    red[tid] = p;
    __syncthreads();
    for (int s = 128; s > 0; s >>= 1) {
      if (tid < s) red[tid] += red[tid + s];
      __syncthreads();
    }
    if (tid == 0) c0[0] = red[0] + (double)b2[0];
  }
}

// ---------------- K1: row dots, 16 lanes per row ----------------
// Thread owns segment s (16 elements) of 4 rows; v-slice registered once.
// 4-step butterfly over the 16-lane group combines 4 rows at a time:
// ~5 b32 DS ops per row (vs ~24 for full-wave fp64 butterflies).
__global__ void __launch_bounds__(256) k1_rowdots(
    const float* __restrict__ x, const double* __restrict__ vd,
    double* __restrict__ d1, double* __restrict__ d2, float* __restrict__ absS) {
  int tid = threadIdx.x;
  int s = tid & 15;          // segment within row
  int slot = tid >> 4;       // 16 row-slots x 4 rows = 64 rows per block
  long rowBase = (long)blockIdx.x * 64;

  double v12[16], v2v[16];   // my 16-element slice of v2 and (v1+v2)
#pragma unroll
  for (int k = 0; k < 16; ++k) {
    double bv = vd[256 + s * 16 + k];
    v2v[k] = bv;
    v12[k] = vd[s * 16 + k] + bv;
  }

#pragma unroll
  for (int i = 0; i < 4; ++i) {
    long row = rowBase + slot * 4 + i;
    const float4* xr = (const float4*)(x + row * H_ + s * 16);
    float4 a0 = xr[0], a1 = xr[1], a2 = xr[2], a3 = xr[3];
    float e[16];
    *(float4*)(e + 0) = a0; *(float4*)(e + 4) = a1;
    *(float4*)(e + 8) = a2; *(float4*)(e + 12) = a3;
    double p1 = 0.0, p2 = 0.0;
    bool nz = false;
#pragma unroll
    for (int k = 0; k < 16; ++k) {
      p1 += (double)e[k] * v12[k];
      p2 += (double)e[k] * v2v[k];
      nz |= (e[k] != 0.0f);
    }
    float nzf = nz ? 1.0f : 0.0f;
#pragma unroll
    for (int off = 1; off < 16; off <<= 1) {  // stays inside the 16-group
      p1 += __shfl_xor(p1, off, 64);
      p2 += __shfl_xor(p2, off, 64);
      nzf += __shfl_xor(nzf, off, 64);
    }
    if (s == 0) {
      d1[row] = p1;
      d2[row] = p2;
      absS[row] = (nzf > 0.0f) ? 1.0f : 0.0f;
    }
  }
}

// ---------------- K2: weights + EXACT parallel fire solve (1 block / b) --
// prev_t = S_t - C_t identically, so C_t = min(C_{t-1}+1, Kp_t) with
// Kp_t = max(0, ceil(S_t - 1)) nondecreasing. Exact solution:
//   C_t = t + min(1, M_t),  M_t = min_{s<=t}(Kp_s - s).   (any a_t >= 0)
__global__ void __launch_bounds__(256) k2_weights(
    const double* __restrict__ d1, const double* __restrict__ d2,
    const float* __restrict__ absS, const float* __restrict__ mask,
    const int* __restrict__ is_tr, const double* __restrict__ c0p,
    float* __restrict__ o_ori, float* __restrict__ o_sa, float* __restrict__ o_ff,
    float* __restrict__ wsc, int* __restrict__ fireT,
    int* __restrict__ nAllArr, int* __restrict__ nUnmArr) {
  __shared__ double s_P[T_];        // prefix sums of d2 (16 KB)
  __shared__ double s_tot[4];       // wave totals (cumsum #1)
  __shared__ double s_red[4][3];    // wave partials: sumA, fpc, maskSum
  __shared__ double s_tot2[4];      // wave totals (cumsum #2)
  __shared__ double s_mtot[4];      // wave mins (min-scan)
  __shared__ int s_int[2];          // [0]=C@firstPad, [1]=nA
  int b = blockIdx.x, tid = threadIdx.x;
  int lane = tid & 63, wv = tid >> 6;
  int t0 = tid * 8;                 // 8 contiguous elements per thread
  const double* d1b = d1 + (long)b * T_;
  const double* d2b = d2 + (long)b * T_;
  const float* asb = absS + (long)b * T_;
  double c0 = c0p[0];

  // ---- prefix sum of d2 -> s_P ----
  double r2[8];
  {
    double run2 = 0.0;
#pragma unroll
    for (int k = 0; k < 8; ++k) { run2 += d2b[t0 + k]; r2[k] = run2; }
    double sc2 = run2;
#pragma unroll
    for (int off = 1; off < 64; off <<= 1) {
      double n = __shfl_up(sc2, off, 64);
      if (lane >= off) sc2 += n;
    }
    if (lane == 63) s_tot[wv] = sc2;
    __syncthreads();
    double base2 = 0.0;
    for (int i = 0; i < wv; ++i) base2 += s_tot[i];
    double e2 = base2 + (sc2 - run2);
#pragma unroll
    for (int k = 0; k < 8; ++k) s_P[t0 + k] = e2 + r2[k];
  }
  __syncthreads();

  // ---- Part A: w = clip(relu(d1 - windowmean + c0), 0, 1); windowsum via P
  double wd[8];
  double sa = 0.0, fpc = 0.0;
#pragma unroll
  for (int k = 0; k < 8; ++k) {
    int t = t0 + k;
    double wvv;
    if (t == 0) {
      wvv = d1b[0] - s_P[0] + c0;  // hist[0] = x[0]
    } else {
      int start = t - 10; if (start < 0) start = 0;
      double ws_ = s_P[t - 1] - (start > 0 ? s_P[start - 1] : 0.0);
      wvv = d1b[t] - ws_ / (double)(t - start) + c0;
    }
    wvv = wvv < 0.0 ? 0.0 : (wvv > 1.0 ? 1.0 : wvv);
    wd[k] = wvv;
    sa += wvv;
    fpc += (asb[t] != 0.0f) ? 1.0 : 0.0;
  }
  {  // o_ori: two float4 stores (contiguous 8)
    float4* ov = (float4*)(o_ori + (long)b * T_ + t0);
    ov[0] = make_float4((float)wd[0], (float)wd[1], (float)wd[2], (float)wd[3]);
    ov[1] = make_float4((float)wd[4], (float)wd[5], (float)wd[6], (float)wd[7]);
  }
  // ---- reductions via wave shuffles (sumA, firstPad count, maskSum)
  double ms = (tid < 200) ? (double)mask[(long)b * 200 + tid] : 0.0;
  double sar = waveReduceD(sa), fpr = waveReduceD(fpc), msr = waveReduceD(ms);
  if (lane == 0) { s_red[wv][0] = sar; s_red[wv][1] = fpr; s_red[wv][2] = msr; }
  __syncthreads();
  double sumA = s_red[0][0] + s_red[1][0] + s_red[2][0] + s_red[3][0];
  double fpD  = s_red[0][1] + s_red[1][1] + s_red[2][1] + s_red[3][1];
  double maskSum = s_red[0][2] + s_red[1][2] + s_red[2][2] + s_red[3][2];
  if (tid == 0) o_sa[b] = (float)sumA;
  int firstPad = (int)(fpD + 0.5);
  double scale;
  if (is_tr[0] != 0) {
    scale = (sumA == 0.0) ? 0.0 : (maskSum - 1.0) / (sumA > 1e-8 ? sumA : 1e-8);
  } else {
    scale = 1.0;
  }

  // ---- scaled + pad-masked a; write wsc; cumsum -> S_t
  double a[8], r[8];
  double run = 0.0;
#pragma unroll
  for (int k = 0; k < 8; ++k) {
    int t = t0 + k;
    double av = wd[k] * scale;
    if (t > firstPad) av = 0.0;
    a[k] = av;
    run += av; r[k] = run;
  }
  {  // wsc: two float4 stores
    float4* wvv = (float4*)(wsc + (long)b * T_ + t0);
    wvv[0] = make_float4((float)a[0], (float)a[1], (float)a[2], (float)a[3]);
    wvv[1] = make_float4((float)a[4], (float)a[5], (float)a[6], (float)a[7]);
  }
  double sc = run;
#pragma unroll
  for (int off = 1; off < 64; off <<= 1) {
    double n = __shfl_up(sc, off, 64);
    if (lane >= off) sc += n;
  }
  if (lane == 63) s_tot2[wv] = sc;
  __syncthreads();
  double base = 0.0;
  for (int i = 0; i < wv; ++i) base += s_tot2[i];
  double e = base + (sc - run);  // exclusive prefix for this thread

  // ---- D_t = Kp_t - t, prefix-min scan -> M_t, C_t = t + min(1, M_t)
  double m[8];
  double mn = 1e300;
#pragma unroll
  for (int k = 0; k < 8; ++k) {
    double S = e + r[k];
    double kp = ceil(S - 1.0); if (kp < 0.0) kp = 0.0;
    double D = kp - (double)(t0 + k);
    mn = fmin(mn, D);
    m[k] = mn;
  }
  double scm = mn;
#pragma unroll
  for (int off = 1; off < 64; off <<= 1) {
    double n = __shfl_up(scm, off, 64);
    if (lane >= off) scm = fmin(scm, n);
  }
  double exw = __shfl_up(scm, 1, 64);       // wave-exclusive inclusive-min
  if (lane == 0) exw = 1e300;
  if (lane == 63) s_mtot[wv] = scm;
  __syncthreads();
  double mbase = 1e300;
  for (int i = 0; i < wv; ++i) mbase = fmin(mbase, s_mtot[i]);
  double Mexcl = fmin(mbase, exw);          // min over s < t0

  // ---- fires ----
  float flags[8];
  int Cp = (t0 - 1) + (int)fmin(1.0, Mexcl);  // t0==0: Mexcl=inf -> C_{-1}=0
#pragma unroll
  for (int k = 0; k < 8; ++k) {
    int t = t0 + k;
    double Mk = fmin(Mexcl, m[k]);
    int C = t + (int)fmin(1.0, Mk);
    bool fired = C > Cp;
    flags[k] = fired ? 1.0f : 0.0f;
    if (fired) fireT[(long)b * T_ + (C - 1)] = t;
    if (t == firstPad) s_int[0] = C;
    Cp = C;
  }
  {  // o_ff: two float4 stores
    float4* fv = (float4*)(o_ff + (long)b * T_ + t0);
    fv[0] = make_float4(flags[0], flags[1], flags[2], flags[3]);
    fv[1] = make_float4(flags[4], flags[5], flags[6], flags[7]);
  }
  if (tid == 255) s_int[1] = Cp;  // nA = C_{T-1}
  __syncthreads();
  if (tid == 0) {
    int nA = s_int[1];
    nAllArr[b] = nA;
    nUnmArr[b] = (firstPad >= T_) ? nA : s_int[0];
  }
}

// ---------------- K4: ALL cif rows (work rows + zero rows) ----------------
// grid (ceil(L/4), B), 256 threads = 4 waves, one pos per wave. Full
// coverage of cif + notpad -> no memset needed. Nontemporal stores keep the
// 67 MB cif stream from evicting x out of L2/L3 (k4 re-reads x after k1).
__global__ void __launch_bounds__(256) k4_rows(
    const float* __restrict__ x, const float* __restrict__ wsc,
    const int* __restrict__ fireT,
    const int* __restrict__ nAllArr, const int* __restrict__ nUnmArr,
    float* __restrict__ cif, float* __restrict__ notpad) {
  int wave = threadIdx.x >> 6, lane = threadIdx.x & 63;
  int pos = blockIdx.x * 4 + wave;
  int b = blockIdx.y;
  if (pos >= L_) return;
  int nA = nAllArr[b], nU = nUnmArr[b];
  float* crow = cif + ((long)b * L_ + pos) * H_ + lane * 4;
  if (pos > nU) {
    nt_store4(make_float4(0.0f, 0.0f, 0.0f, 0.0f), crow);
    if (lane == 0) notpad[(long)b * L_ + pos] = 0.0f;
    return;
  }
  const int* ftb = fireT + (long)b * T_;
  int hi, anchor, lo;
  if (pos < nU) {
    hi = ftb[pos];
    anchor = (pos == 0) ? 0 : ftb[pos - 1];
    lo = (pos == 0) ? 0 : anchor + 1;
  } else {
    hi = T_ - 1;                       // final carry state fin_s
    anchor = (nA == 0) ? 0 : ftb[nA - 1];
    lo = (nA == 0) ? 0 : anchor + 1;
  }
  const float* xb = x + (long)b * T_ * H_;
  float4 acc = ((const float4*)(xb + (long)anchor * H_))[lane];
  float4 acc2 = make_float4(0.0f, 0.0f, 0.0f, 0.0f);
  const float* wb = wsc + (long)b * T_;
  int u = lo;
  for (; u + 1 <= hi; u += 2) {   // dual accumulators: half the dep chain
    float f0 = 1.0f - wb[u];
    float f1 = 1.0f - wb[u + 1];
    float4 xv0 = ((const float4*)(xb + (long)u * H_))[lane];
    float4 xv1 = ((const float4*)(xb + (long)(u + 1) * H_))[lane];
    acc.x += f0 * xv0.x;  acc.y += f0 * xv0.y;
    acc.z += f0 * xv0.z;  acc.w += f0 * xv0.w;
    acc2.x += f1 * xv1.x; acc2.y += f1 * xv1.y;
    acc2.z += f1 * xv1.z; acc2.w += f1 * xv1.w;
  }
  if (u <= hi) {
    float f = 1.0f - wb[u];
    float4 xv = ((const float4*)(xb + (long)u * H_))[lane];
    acc.x += f * xv.x; acc.y += f * xv.y; acc.z += f * xv.z; acc.w += f * xv.w;
  }
  acc.x += acc2.x; acc.y += acc2.y; acc.z += acc2.z; acc.w += acc2.w;
  float ss = acc.x * acc.x + acc.y * acc.y + acc.z * acc.z + acc.w * acc.w;
#pragma unroll
  for (int off = 32; off > 0; off >>= 1) ss += __shfl_xor(ss, off, 64);
  float inv = 1.0f / fmaxf(sqrtf(ss), 1e-12f);
  nt_store4(make_float4(acc.x * inv, acc.y * inv, acc.z * inv, acc.w * inv), crow);
  if (lane == 0) notpad[(long)b * L_ + pos] = 1.0f;
}

// ---------------- launch ----------------
extern "C" void kernel_launch(void* const* d_in, const int* in_sizes, int n_in,
                              void* d_out, int out_size, void* d_ws, size_t ws_size,
                              hipStream_t stream) {
  const float* x    = (const float*)d_in[0];
  const float* mask = (const float*)d_in[1];
  const float* W1   = (const float*)d_in[2];
  const float* b1   = (const float*)d_in[3];
  const float* W2   = (const float*)d_in[4];
  const float* b2   = (const float*)d_in[5];
  const int*   istr = (const int*)d_in[6];

  float* out = (float*)d_out;
  // output layout (all fp32, concatenated in return order)
  float* o_cif = out;                                  // B*L*H
  float* o_ori = o_cif + (size_t)B_ * L_ * H_;         // B*T
  float* o_ff  = o_ori + (size_t)B_ * T_;              // B*T
  float* o_np  = o_ff  + (size_t)B_ * T_;              // B*L
  float* o_sa  = o_np  + (size_t)B_ * L_;              // B

  // workspace layout
  char* w = (char*)d_ws;
  double* vd   = (double*)w; w += 512 * 8;
  double* c0   = (double*)w; w += 8;
  double* d1   = (double*)w; w += (size_t)B_ * T_ * 8;
  double* d2   = (double*)w; w += (size_t)B_ * T_ * 8;
  float* absS  = (float*)w;  w += (size_t)B_ * T_ * 4;
  float* wsc   = (float*)w;  w += (size_t)B_ * T_ * 4;
  int* fireT   = (int*)w;    w += (size_t)B_ * T_ * 4;
  int* nAllA   = (int*)w;    w += B_ * 4;
  int* nUnmA   = (int*)w;    w += B_ * 4;

  // no memset: k2 covers o_ori/o_ff/o_sa; k4 covers every cif row + o_np.
  k0_fold<<<16, 256, 0, stream>>>(W1, b1, W2, b2, vd, c0);
  k1_rowdots<<<(B_ * T_) / 64, 256, 0, stream>>>(x, vd, d1, d2, absS);
  k2_weights<<<B_, 256, 0, stream>>>(d1, d2, absS, mask, istr, c0,
                                     o_ori, o_sa, o_ff, wsc, fireT,
                                     nAllA, nUnmA);
  k4_rows<<<dim3((L_ + 3) / 4, B_), 256, 0, stream>>>(
      x, wsc, fireT, nAllA, nUnmA, o_cif, o_np);
}